// Round 9
// baseline (229.083 us; speedup 1.0000x reference)
//
#include <hip/hip_runtime.h>
#include <math.h>

#define BSZ 2
#define CDIM 256
#define LSEQ 4096
#define DIN 512
#define NST 16
#define NC 256          // scan chunks per batch (CT=16)
#define CT 16
#define LOG2E 1.44269504088896f

typedef unsigned short ushort_t;
typedef short s16x8 __attribute__((ext_vector_type(8)));
typedef float f32x4 __attribute__((ext_vector_type(4)));

__device__ inline ushort_t f2bf(float f) {
    union { float f; unsigned u; } v; v.f = f;
    unsigned r = v.u + 0x7FFF + ((v.u >> 16) & 1);
    return (ushort_t)(r >> 16);
}
__device__ inline float bf2f(ushort_t u) {
    union { unsigned u; float f; } v; v.u = ((unsigned)u) << 16;
    return v.f;
}

// ---------------- prep + layernorm in one kernel ----------------
__device__ inline void tile_tr(const float* __restrict__ src, ushort_t* __restrict__ dst,
                               int R, int C, int c0, int r0, int tid) {
    __shared__ float T[32][33];
    int tx = tid & 31, ty = tid >> 5;
    #pragma unroll
    for (int i = 0; i < 4; ++i)
        T[ty + i * 8][tx] = src[(r0 + ty + i * 8) * C + c0 + tx];
    __syncthreads();
    #pragma unroll
    for (int i = 0; i < 4; ++i)
        dst[(c0 + ty + i * 8) * R + r0 + tx] = f2bf(T[tx][ty + i * 8]);
}

__global__ __launch_bounds__(256) void k_prep(const float* __restrict__ x,
                                              const float* __restrict__ g,
                                              const float* __restrict__ beta,
                                              const float* __restrict__ W_in,
                                              const float* __restrict__ W_out,
                                              const float* __restrict__ W_x,
                                              ushort_t* __restrict__ xsb,
                                              ushort_t* __restrict__ Wt1,
                                              ushort_t* __restrict__ Wt3,
                                              ushort_t* __restrict__ Wxt) {
    int bi = blockIdx.x, tid = threadIdx.x;
    if (bi >= 256) {
        if (bi < 512) {
            int rem = bi - 256;
            tile_tr(W_in, Wt1, 256, 1024, (rem & 31) * 32, (rem >> 5) * 32, tid);
        } else if (bi < 640) {
            int rem = bi - 512;
            tile_tr(W_out, Wt3, 512, 256, (rem & 7) * 32, (rem >> 3) * 32, tid);
        } else {
            int f = (bi - 640) * 256 + tid;
            int n = f >> 9, dcol = f & 511;
            Wxt[n * 512 + dcol] = f2bf(W_x[dcol * 48 + n]);
        }
        return;
    }
    int b  = bi >> 7;
    int l0 = (bi & 127) * 32;
    __shared__ float T[256][33];
    __shared__ float ps[8][32], ps2[8][32];
    __shared__ float mus[32], rs[32];
    #pragma unroll
    for (int i = 0; i < 8; ++i) {
        int f = i * 256 + tid;
        int c = f >> 3, lq = f & 7;
        float4 v = *(const float4*)(x + (b * 256 + c) * 4096 + l0 + lq * 4);
        T[c][lq * 4 + 0] = v.x; T[c][lq * 4 + 1] = v.y;
        T[c][lq * 4 + 2] = v.z; T[c][lq * 4 + 3] = v.w;
    }
    __syncthreads();
    {
        int lt = tid & 31, q = tid >> 5;
        float s = 0.f, s2 = 0.f;
        #pragma unroll
        for (int c = q * 32; c < q * 32 + 32; ++c) {
            float v = T[c][lt];
            s += v; s2 += v * v;
        }
        ps[q][lt] = s; ps2[q][lt] = s2;
    }
    __syncthreads();
    if (tid < 32) {
        float ts = 0.f, ts2 = 0.f;
        #pragma unroll
        for (int q = 0; q < 8; ++q) { ts += ps[q][tid]; ts2 += ps2[q][tid]; }
        float mu  = ts * (1.f / 256.f);
        float var = ts2 * (1.f / 256.f) - mu * mu;
        mus[tid] = mu;
        rs[tid]  = rsqrtf(var + 1e-5f);
    }
    __syncthreads();
    float gg = g[tid], bb = beta[tid];
    #pragma unroll
    for (int i = 0; i < 32; ++i) {
        float v = (T[tid][i] - mus[i]) * rs[i] * gg + bb;
        xsb[(b * 4096 + l0 + i) * 256 + tid] = f2bf(v);
    }
}

// ---------------- GEMM1 (MFMA bf16) with vectorized LDS-transpose epilogue -
__global__ __launch_bounds__(256) void k_gemm1(const ushort_t* __restrict__ Abf,
                                               const ushort_t* __restrict__ Wt,
                                               ushort_t* __restrict__ xinb,
                                               ushort_t* __restrict__ zb) {
    __shared__ ushort_t As[128][40];
    __shared__ ushort_t Bs[128][40];
    __shared__ ushort_t Ct[128][136];
    int tid = threadIdx.x;
    int m0 = blockIdx.x * 128;
    int n0 = blockIdx.y * 128;
    int lane = tid & 63, w = tid >> 6;
    int wr = w >> 1, wc = w & 1;
    int quad = lane >> 4, lm = lane & 15;
    f32x4 acc[4][4] = {};
    for (int k0 = 0; k0 < 256; k0 += 32) {
        #pragma unroll
        for (int i = 0; i < 2; ++i) {
            int c = i * 256 + tid;
            int r = c >> 2, kq = c & 3;
            *(uint4*)&As[r][kq * 8] = *(const uint4*)&Abf[(m0 + r) * 256 + k0 + kq * 8];
            *(uint4*)&Bs[r][kq * 8] = *(const uint4*)&Wt[(n0 + r) * 256 + k0 + kq * 8];
        }
        __syncthreads();
        s16x8 af[4], bf_[4];
        #pragma unroll
        for (int mi = 0; mi < 4; ++mi)
            af[mi] = *(const s16x8*)&As[wr * 64 + mi * 16 + lm][quad * 8];
        #pragma unroll
        for (int ni = 0; ni < 4; ++ni)
            bf_[ni] = *(const s16x8*)&Bs[wc * 64 + ni * 16 + lm][quad * 8];
        #pragma unroll
        for (int mi = 0; mi < 4; ++mi)
            #pragma unroll
            for (int ni = 0; ni < 4; ++ni)
                acc[mi][ni] = __builtin_amdgcn_mfma_f32_16x16x32_bf16(
                    af[mi], bf_[ni], acc[mi][ni], 0, 0, 0);
        __syncthreads();
    }
    #pragma unroll
    for (int mi = 0; mi < 4; ++mi)
        #pragma unroll
        for (int ni = 0; ni < 4; ++ni)
            #pragma unroll
            for (int r = 0; r < 4; ++r)
                Ct[wr * 64 + mi * 16 + quad * 4 + r][wc * 64 + ni * 16 + lm] =
                    f2bf(acc[mi][ni][r]);
    __syncthreads();
    bool isz = (n0 >= 512);
    ushort_t* outp = isz ? zb : xinb;
    int nb = isz ? n0 - 512 : n0;
    #pragma unroll
    for (int i = 0; i < 8; ++i) {
        int f = i * 256 + tid;
        int row = f >> 4, q = f & 15;
        *(uint4*)&outp[(m0 + row) * 512 + nb + q * 8] = *(uint4*)&Ct[row][q * 8];
    }
}

// ---------------- depthwise causal conv(4) + SiLU, 8-wide vectorized -------
// thread handles 8 consecutive d for one token. grid 2048 x 256.
__global__ __launch_bounds__(256) void k_conv(const ushort_t* __restrict__ xinb,
                                              const float* __restrict__ cw,
                                              const float* __restrict__ cb,
                                              ushort_t* __restrict__ xcb) {
    int gid = blockIdx.x * 256 + threadIdx.x;    // B*L*64
    int dq = gid & 63;                            // d-octet
    int r = gid >> 6;
    int l = r & 4095;
    int b = r >> 12;
    int d0 = dq * 8;
    float s[8];
    #pragma unroll
    for (int j = 0; j < 8; ++j) s[j] = cb[d0 + j];
    #pragma unroll
    for (int k = 0; k < 4; ++k) {
        int ll = l - 3 + k;
        if (ll >= 0) {
            uint4 v = *(const uint4*)&xinb[(((b << 12) + ll) << 9) + d0];
            const ushort_t* pv = (const ushort_t*)&v;
            #pragma unroll
            for (int j = 0; j < 8; ++j)
                s[j] += cw[(d0 + j) * 4 + k] * bf2f(pv[j]);
        }
    }
    ushort_t outv[8];
    #pragma unroll
    for (int j = 0; j < 8; ++j) {
        float sig = 1.f / (1.f + expf(-s[j]));
        outv[j] = f2bf(s[j] * sig);
    }
    *(uint4*)&xcb[(((b << 12) + l) << 9) + d0] = *(uint4*)outv;
}

// ---------------- x-proj (MFMA): dbl = xc @ W_x -> dtr/Bm/Cm ---------------
__global__ __launch_bounds__(256) void k_xproj1(const ushort_t* __restrict__ xcb,
                                                const ushort_t* __restrict__ Wxt,
                                                float* __restrict__ dtr,
                                                float* __restrict__ Bm,
                                                float* __restrict__ Cm) {
    __shared__ ushort_t As[64][72];
    __shared__ ushort_t Bs[48][72];
    int tid = threadIdx.x;
    int m0 = blockIdx.x * 64;
    int lane = tid & 63, w = tid >> 6;
    int quad = lane >> 4, lm = lane & 15;
    f32x4 acc[3] = {};
    for (int k0 = 0; k0 < 512; k0 += 64) {
        #pragma unroll
        for (int i = 0; i < 2; ++i) {
            int f = i * 256 + tid;
            int r = f >> 3, kq = f & 7;
            *(uint4*)&As[r][kq * 8] = *(const uint4*)&xcb[(m0 + r) * 512 + k0 + kq * 8];
        }
        if (tid < 192) {
            #pragma unroll
            for (int i = 0; i < 2; ++i) {
                int f = i * 192 + tid;
                int r = f >> 3, kq = f & 7;
                *(uint4*)&Bs[r][kq * 8] = *(const uint4*)&Wxt[r * 512 + k0 + kq * 8];
            }
        }
        __syncthreads();
        #pragma unroll
        for (int kk = 0; kk < 2; ++kk) {
            s16x8 af = *(const s16x8*)&As[w * 16 + lm][kk * 32 + quad * 8];
            #pragma unroll
            for (int nt = 0; nt < 3; ++nt) {
                s16x8 bv = *(const s16x8*)&Bs[nt * 16 + lm][kk * 32 + quad * 8];
                acc[nt] = __builtin_amdgcn_mfma_f32_16x16x32_bf16(af, bv, acc[nt], 0, 0, 0);
            }
        }
        __syncthreads();
    }
    #pragma unroll
    for (int nt = 0; nt < 3; ++nt) {
        float* dst = (nt == 0) ? dtr : ((nt == 1) ? Bm : Cm);
        #pragma unroll
        for (int r = 0; r < 4; ++r) {
            int row = m0 + w * 16 + quad * 4 + r;
            dst[row * 16 + lm] = acc[nt][r];
        }
    }
}

// ---------------- dt-proj: dtp = softplus(dtr @ W_dt + b_dt) -> bf16 -------
__global__ __launch_bounds__(256) void k_dtproj(const float* __restrict__ dtr,
                                                const float* __restrict__ Wdt,
                                                const float* __restrict__ bdt,
                                                ushort_t* __restrict__ dtp) {
    int tid = threadIdx.x;
    int t0 = blockIdx.x * 16;
    __shared__ float R[16][17];
    float w0[16], w1[16];
    #pragma unroll
    for (int r = 0; r < 16; ++r) {
        w0[r] = Wdt[r * 512 + tid];
        w1[r] = Wdt[r * 512 + 256 + tid];
    }
    float b0 = bdt[tid], b1 = bdt[256 + tid];
    {
        int t = tid >> 4, r = tid & 15;
        R[t][r] = dtr[(t0 + t) * 16 + r];
    }
    __syncthreads();
    for (int t = 0; t < 16; ++t) {
        float s0 = b0, s1 = b1;
        #pragma unroll
        for (int r = 0; r < 16; ++r) {
            float dv = R[t][r];
            s0 += dv * w0[r];
            s1 += dv * w1[r];
        }
        s0 = (s0 > 20.f) ? s0 : log1pf(expf(s0));
        s1 = (s1 > 20.f) ? s1 : log1pf(expf(s1));
        dtp[(t0 + t) * 512 + tid] = f2bf(s0);
        dtp[(t0 + t) * 512 + 256 + tid] = f2bf(s1);
    }
}

// ---------------- scan phase A: CT=16, 512 blocks, register staged ---------
__global__ __launch_bounds__(512) void k_scanA(const ushort_t* __restrict__ dtp,
                                               const ushort_t* __restrict__ xcb,
                                               const float* __restrict__ Bm,
                                               const float* __restrict__ A_log,
                                               float* __restrict__ S,
                                               float* __restrict__ sdt) {
    int b = blockIdx.x >> 8;
    int ch = blockIdx.x & 255;
    int d = threadIdx.x;
    __shared__ float Bb[CT][16];
    if (threadIdx.x < 256) {
        int t = threadIdx.x >> 4, n = threadIdx.x & 15;
        Bb[t][n] = Bm[((b << 12) + ch * CT + t) * 16 + n];
    }
    __syncthreads();
    int base = ((b << 12) + ch * CT) * 512 + d;
    float dv_[CT], xv_[CT];
    #pragma unroll
    for (int t = 0; t < CT; ++t) {
        dv_[t] = bf2f(dtp[base + t * 512]);
        xv_[t] = bf2f(xcb[base + t * 512]);
    }
    float a2[16];
    #pragma unroll
    for (int n = 0; n < 16; ++n) a2[n] = -expf(A_log[d * 16 + n]) * LOG2E;
    float h[16] = {};
    float sum_dt = 0.f;
    #pragma unroll
    for (int t = 0; t < CT; ++t) {
        float dv = dv_[t];
        float dx = dv * xv_[t];
        sum_dt += dv;
        #pragma unroll
        for (int n = 0; n < 16; ++n) {
            float w = exp2f(dv * a2[n]);
            h[n] = w * h[n] + dx * Bb[t][n];
        }
    }
    int so = ((b * NC + ch) * 16) * 512 + d;
    #pragma unroll
    for (int n = 0; n < 16; ++n)
        S[so + n * 512] = h[n];
    sdt[(b * NC + ch) * 512 + d] = sum_dt;
}

// ---------------- comb phase A: per-segment compose (16 chunks) ------------
__global__ __launch_bounds__(512) void k_combA(const float* __restrict__ S,
                                               const float* __restrict__ sdt,
                                               const float* __restrict__ A_log,
                                               float* __restrict__ Wsg,
                                               float* __restrict__ Ssg) {
    int bi = blockIdx.x;
    int b = bi >> 8, n = (bi >> 4) & 15, seg = bi & 15;
    int d = threadIdx.x;
    float a2 = -expf(A_log[d * 16 + n]) * LOG2E;
    float sv_[16], wv_[16];
    #pragma unroll
    for (int i = 0; i < 16; ++i) {
        int c = seg * 16 + i;
        wv_[i] = exp2f(a2 * sdt[(b * NC + c) * 512 + d]);
        sv_[i] = S[((b * NC + c) * 16 + n) * 512 + d];
    }
    float Wc = 1.f, Sc = 0.f;
    #pragma unroll
    for (int i = 0; i < 16; ++i) {
        Sc = wv_[i] * Sc + sv_[i];
        Wc *= wv_[i];
    }
    int o = ((b * 16 + n) * 16 + seg) * 512 + d;
    Wsg[o] = Wc;
    Ssg[o] = Sc;
}

// ---------------- comb phase C: prefix + replay, hinit in place in S -------
__global__ __launch_bounds__(512) void k_combC(float* S,
                                               const float* __restrict__ sdt,
                                               const float* __restrict__ A_log,
                                               const float* __restrict__ Wsg,
                                               const float* __restrict__ Ssg) {
    int bi = blockIdx.x;
    int b = bi >> 8, n = (bi >> 4) & 15, seg = bi & 15;
    int d = threadIdx.x;
    float a2 = -expf(A_log[d * 16 + n]) * LOG2E;
    float sval[16], wv[16];
    #pragma unroll
    for (int i = 0; i < 16; ++i) {
        int c = seg * 16 + i;
        sval[i] = S[((b * NC + c) * 16 + n) * 512 + d];
        wv[i]   = exp2f(a2 * sdt[(b * NC + c) * 512 + d]);
    }
    float h = 0.f;
    int o0 = ((b * 16 + n) * 16) * 512 + d;
    for (int s = 0; s < seg; ++s)
        h = Wsg[o0 + s * 512] * h + Ssg[o0 + s * 512];
    #pragma unroll
    for (int i = 0; i < 16; ++i) {
        int c = seg * 16 + i;
        S[((b * NC + c) * 16 + n) * 512 + d] = h;
        h = wv[i] * h + sval[i];
    }
}

// ---------------- scan phase C: replay + skip + SiLU gate -> bf16 ----------
__global__ __launch_bounds__(512) void k_scanC(const ushort_t* __restrict__ dtp,
                                               const ushort_t* __restrict__ xcb,
                                               const float* __restrict__ Bm,
                                               const float* __restrict__ Cm,
                                               const float* __restrict__ A_log,
                                               const float* __restrict__ hinit,
                                               const float* __restrict__ Dskip,
                                               const ushort_t* __restrict__ zb,
                                               ushort_t* __restrict__ yact) {
    int b = blockIdx.x >> 8;
    int ch = blockIdx.x & 255;
    int d = threadIdx.x;
    __shared__ float Bb[CT][16], Cb[CT][16];
    if (threadIdx.x < 256) {
        int t = threadIdx.x >> 4, n = threadIdx.x & 15;
        int li = ((b << 12) + ch * CT + t) * 16 + n;
        Bb[t][n] = Bm[li];
        Cb[t][n] = Cm[li];
    }
    __syncthreads();
    int base = ((b << 12) + ch * CT) * 512 + d;
    float dv_[CT], xv_[CT], zv_[CT];
    #pragma unroll
    for (int t = 0; t < CT; ++t) {
        dv_[t] = bf2f(dtp[base + t * 512]);
        xv_[t] = bf2f(xcb[base + t * 512]);
        zv_[t] = bf2f(zb[base + t * 512]);
    }
    float a2[16], h[16];
    #pragma unroll
    for (int n = 0; n < 16; ++n) a2[n] = -expf(A_log[d * 16 + n]) * LOG2E;
    int hi = ((b * NC + ch) * 16) * 512 + d;
    #pragma unroll
    for (int n = 0; n < 16; ++n) h[n] = hinit[hi + n * 512];
    float Dsk = Dskip[d];
    #pragma unroll
    for (int t = 0; t < CT; ++t) {
        float dv = dv_[t];
        float xv = xv_[t];
        float zv = zv_[t];
        float dx = dv * xv;
        float y = 0.f;
        #pragma unroll
        for (int n = 0; n < 16; ++n) {
            float w = exp2f(dv * a2[n]);
            h[n] = w * h[n] + dx * Bb[t][n];
            y += h[n] * Cb[t][n];
        }
        y += xv * Dsk;
        float sig = 1.f / (1.f + expf(-zv));
        yact[base + t * 512] = f2bf(y * zv * sig);
    }
}

// ---------------- GEMM3 (MFMA bf16): out = yact @ W_out, transposed store --
__global__ __launch_bounds__(256) void k_gemm3(const ushort_t* __restrict__ Abf,
                                               const ushort_t* __restrict__ Wt3,
                                               float* __restrict__ out) {
    __shared__ ushort_t As[128][40];
    __shared__ ushort_t Bs[64][40];
    __shared__ float T[64][132];
    int tid = threadIdx.x;
    int m0 = blockIdx.x * 128;
    int n0 = blockIdx.y * 64;
    int lane = tid & 63, w = tid >> 6;
    int wr = w >> 1, wc = w & 1;
    int quad = lane >> 4, lm = lane & 15;
    f32x4 acc[4][2] = {};
    for (int k0 = 0; k0 < 512; k0 += 32) {
        #pragma unroll
        for (int i = 0; i < 2; ++i) {
            int c = i * 256 + tid;
            int r = c >> 2, kq = c & 3;
            *(uint4*)&As[r][kq * 8] = *(const uint4*)&Abf[(m0 + r) * 512 + k0 + kq * 8];
        }
        {
            int r = tid >> 2, kq = tid & 3;
            *(uint4*)&Bs[r][kq * 8] = *(const uint4*)&Wt3[(n0 + r) * 512 + k0 + kq * 8];
        }
        __syncthreads();
        s16x8 af[4], bf_[2];
        #pragma unroll
        for (int mi = 0; mi < 4; ++mi)
            af[mi] = *(const s16x8*)&As[wr * 64 + mi * 16 + lm][quad * 8];
        #pragma unroll
        for (int ni = 0; ni < 2; ++ni)
            bf_[ni] = *(const s16x8*)&Bs[wc * 32 + ni * 16 + lm][quad * 8];
        #pragma unroll
        for (int mi = 0; mi < 4; ++mi)
            #pragma unroll
            for (int ni = 0; ni < 2; ++ni)
                acc[mi][ni] = __builtin_amdgcn_mfma_f32_16x16x32_bf16(
                    af[mi], bf_[ni], acc[mi][ni], 0, 0, 0);
        __syncthreads();
    }
    #pragma unroll
    for (int mi = 0; mi < 4; ++mi)
        #pragma unroll
        for (int ni = 0; ni < 2; ++ni)
            #pragma unroll
            for (int r = 0; r < 4; ++r)
                T[wc * 32 + ni * 16 + lm][wr * 64 + mi * 16 + quad * 4 + r] = acc[mi][ni][r];
    __syncthreads();
    int b = m0 >> 12;
    int l0 = m0 & 4095;
    #pragma unroll
    for (int i = 0; i < 8; ++i) {
        int f = i * 256 + tid;
        int col = f >> 5, lq = f & 31;
        float4 v = *(float4*)&T[col][lq * 4];
        *(float4*)(out + b * (256 * 4096) + (n0 + col) * 4096 + l0 + lq * 4) = v;
    }
}

extern "C" void kernel_launch(void* const* d_in, const int* in_sizes, int n_in,
                              void* d_out, int out_size, void* d_ws, size_t ws_size,
                              hipStream_t stream) {
    const float* x      = (const float*)d_in[0];
    const float* ln_g   = (const float*)d_in[1];
    const float* ln_b   = (const float*)d_in[2];
    const float* W_in   = (const float*)d_in[3];
    const float* conv_w = (const float*)d_in[4];
    const float* conv_b = (const float*)d_in[5];
    const float* W_x    = (const float*)d_in[6];
    const float* W_dt   = (const float*)d_in[7];
    const float* b_dt   = (const float*)d_in[8];
    const float* A_log  = (const float*)d_in[9];
    const float* D_skip = (const float*)d_in[10];
    const float* W_out  = (const float*)d_in[11];
    float* out = (float*)d_out;

    float* ws = (float*)d_ws;
    float* Bm   = ws;                      // 131,072 f
    float* Cm   = Bm + 131072;             // 131,072 f
    float* Sst  = Cm + 131072;             // 4,194,304 f (NC=256; hinit in place)
    float* sdt  = Sst + 4194304;           // 262,144 f
    float* Wsg  = sdt + 262144;            // 262,144 f
    float* Ssg  = Wsg + 262144;            // 262,144 f
    float* dtr  = Ssg + 262144;            // 131,072 f
    ushort_t* xs_bf = (ushort_t*)(dtr + 131072);   // 2,097,152 us
    ushort_t* Wt1  = xs_bf + 2097152;      // 262,144 us
    ushort_t* Wt3  = Wt1 + 262144;         // 131,072 us
    ushort_t* Wxt  = Wt3 + 131072;         // 24,576 us (pad to 32,768)
    ushort_t* xinb = Wxt + 32768;          // 4,194,304 us
    ushort_t* zb   = xinb + 4194304;       // 4,194,304 us
    ushort_t* xcb  = zb + 4194304;         // 4,194,304 us
    ushort_t* dtp  = xcb + 4194304;        // 4,194,304 us
    ushort_t* yact = xinb;                 // alias: xinb dead after conv

    k_prep  <<<dim3(736),   dim3(256), 0, stream>>>(x, ln_g, ln_b, W_in, W_out, W_x,
                                                    xs_bf, Wt1, Wt3, Wxt);
    k_gemm1 <<<dim3(64, 8), dim3(256), 0, stream>>>(xs_bf, Wt1, xinb, zb);
    k_conv  <<<dim3(2048),  dim3(256), 0, stream>>>(xinb, conv_w, conv_b, xcb);
    k_xproj1<<<dim3(128),   dim3(256), 0, stream>>>(xcb, Wxt, dtr, Bm, Cm);
    k_dtproj<<<dim3(512),   dim3(256), 0, stream>>>(dtr, W_dt, b_dt, dtp);
    k_scanA <<<dim3(512),   dim3(512), 0, stream>>>(dtp, xcb, Bm, A_log, Sst, sdt);
    k_combA <<<dim3(512),   dim3(512), 0, stream>>>(Sst, sdt, A_log, Wsg, Ssg);
    k_combC <<<dim3(512),   dim3(512), 0, stream>>>(Sst, sdt, A_log, Wsg, Ssg);
    k_scanC <<<dim3(512),   dim3(512), 0, stream>>>(dtp, xcb, Bm, Cm, A_log, Sst,
                                                    D_skip, zb, yact);
    k_gemm3 <<<dim3(64, 4), dim3(256), 0, stream>>>(yact, Wt3, out);
}